// Round 3
// baseline (3249.368 us; speedup 1.0000x reference)
//
#include <hip/hip_runtime.h>
#include <hip/hip_bf16.h>

static constexpr int S = 64, T = 64, B = 64, E = 256, H = 256, V = 32000;
static constexpr int H4 = 4 * H;          // 1024
static constexpr int NCHUNK = 500;        // V / 64
static constexpr int NROW = (T - 1) * B;  // 4032
static constexpr int LDP = 264;           // LDS row stride (bf16 elems) for MFMA tiles

typedef short bf16x8 __attribute__((ext_vector_type(8)));
typedef float f32x4 __attribute__((ext_vector_type(4)));

__device__ __forceinline__ float sigf(float x) { return 1.0f / (1.0f + __expf(-x)); }
__device__ __forceinline__ float tanhfast(float x) { return 1.0f - 2.0f / (__expf(2.0f * x) + 1.0f); }
__device__ __forceinline__ float bflo(uint w) { return __uint_as_float(w << 16); }
__device__ __forceinline__ float bfhi(uint w) { return __uint_as_float(w & 0xffff0000u); }

// ---------------- f32 -> bf16 convert (flat) ----------------
__global__ __launch_bounds__(256) void k_cvt_bf16(const float* __restrict__ src,
                                                  __hip_bfloat16* __restrict__ dst, int n) {
  int i = blockIdx.x * 256 + threadIdx.x;
  if (i < n) dst[i] = __float2bfloat16(src[i]);
}

// ---------------- f32 [N][512] -> bf16 [N][256] (first-256 slice) -------------
__global__ __launch_bounds__(256) void k_cvt_slice(const float* __restrict__ src,
                                                   __hip_bfloat16* __restrict__ dst) {
  int n = blockIdx.x, tid = threadIdx.x;
  dst[n * 256 + tid] = __float2bfloat16(src[n * 512 + tid]);
}

// ---------------- embedding gather -> bf16 [rows][256] ------------------------
__global__ __launch_bounds__(256) void k_gather(const int* __restrict__ idx,
                                                const float* __restrict__ emb,
                                                __hip_bfloat16* __restrict__ dst) {
  int r = blockIdx.x, tid = threadIdx.x;
  dst[r * 256 + tid] = __float2bfloat16(emb[idx[r] * E + tid]);
}

// ---------------- weight transpose: dst[k][j] = src[j][off+k], bf16 -----------
// grid (R/64, C/64), block 256. dst is [C][R].
__global__ __launch_bounds__(256) void k_wt(const float* __restrict__ src,
                                            __hip_bfloat16* __restrict__ dst,
                                            int R, int src_ld, int src_off) {
  __shared__ float tile[64][65];
  int j0 = blockIdx.x * 64, k0 = blockIdx.y * 64;
  int tid = threadIdx.x;
  for (int i = tid; i < 64 * 64; i += 256) {
    int jj = i >> 6, kk = i & 63;
    tile[jj][kk] = src[(size_t)(j0 + jj) * src_ld + src_off + k0 + kk];
  }
  __syncthreads();
  for (int i = tid; i < 64 * 64; i += 256) {
    int kk = i >> 6, jj = i & 63;
    dst[(size_t)(k0 + kk) * R + j0 + jj] = __float2bfloat16(tile[jj][kk]);
  }
}

// ============ shared MFMA 64x64 tile core (K=256, bf16 in, f32 acc) ===========
#define MFMA_TILE_BODY(Abase, Wbase, rb, cb)                                     \
  const int tid = threadIdx.x;                                                   \
  const int lane = tid & 63, wid = tid >> 6;                                     \
  const int wr = wid >> 1, wc = wid & 1;                                         \
  const int l15 = lane & 15, l4 = lane >> 4;                                     \
  for (int it = 0; it < 8; it++) {                                               \
    int c = it * 256 + tid;                                                      \
    int row = c >> 5, off = (c & 31) * 8;                                        \
    *(uint4*)&Asl[row * LDP + off] =                                             \
        *(const uint4*)((Abase) + (size_t)((rb) + row) * 256 + off);             \
    *(uint4*)&Bsl[row * LDP + off] =                                             \
        *(const uint4*)((Wbase) + (size_t)((cb) + row) * 256 + off);             \
  }                                                                              \
  __syncthreads();                                                               \
  f32x4 acc[2][2];                                                               \
  for (int m = 0; m < 2; m++)                                                    \
    for (int n = 0; n < 2; n++) acc[m][n] = (f32x4){0.f, 0.f, 0.f, 0.f};         \
  for (int kk = 0; kk < 8; kk++) {                                               \
    int ko = kk * 32 + l4 * 8;                                                   \
    bf16x8 a0 = *(const bf16x8*)&Asl[(wr * 32 + l15) * LDP + ko];                \
    bf16x8 a1 = *(const bf16x8*)&Asl[(wr * 32 + 16 + l15) * LDP + ko];           \
    bf16x8 b0 = *(const bf16x8*)&Bsl[(wc * 32 + l15) * LDP + ko];                \
    bf16x8 b1 = *(const bf16x8*)&Bsl[(wc * 32 + 16 + l15) * LDP + ko];           \
    acc[0][0] = __builtin_amdgcn_mfma_f32_16x16x32_bf16(a0, b0, acc[0][0], 0, 0, 0); \
    acc[0][1] = __builtin_amdgcn_mfma_f32_16x16x32_bf16(a0, b1, acc[0][1], 0, 0, 0); \
    acc[1][0] = __builtin_amdgcn_mfma_f32_16x16x32_bf16(a1, b0, acc[1][0], 0, 0, 0); \
    acc[1][1] = __builtin_amdgcn_mfma_f32_16x16x32_bf16(a1, b1, acc[1][1], 0, 0, 0); \
  }

// ---------------- generic GEMM + bias: C f32 = A x W^T + bias -----------------
__global__ __launch_bounds__(256) void k_gemm_bias(
    const __hip_bfloat16* __restrict__ A, const __hip_bfloat16* __restrict__ W,
    const float* __restrict__ bias, float* __restrict__ C, int ldc) {
  __shared__ __align__(16) ushort Asl[64 * LDP];
  __shared__ __align__(16) ushort Bsl[64 * LDP];
  const int cb = blockIdx.x * 64, rb = blockIdx.y * 64;
  MFMA_TILE_BODY((const ushort*)A, (const ushort*)W, rb, cb)
  #pragma unroll
  for (int m = 0; m < 2; m++)
    #pragma unroll
    for (int n = 0; n < 2; n++) {
      int col = cb + wc * 32 + n * 16 + l15;
      float bv = bias[col];
      #pragma unroll
      for (int r = 0; r < 4; r++) {
        int row = rb + wr * 32 + m * 16 + l4 * 4 + r;
        C[(size_t)row * ldc + col] = acc[m][n][r] + bv;
      }
    }
}

// ---------------- vocab GEMM + fused chunk logsumexp + gold capture -----------
__global__ __launch_bounds__(256) void k_vocab_mfma(
    const __hip_bfloat16* __restrict__ outs_bf, const __hip_bfloat16* __restrict__ Wv,
    const int* __restrict__ tgt, float* __restrict__ part_max,
    float* __restrict__ part_sum, float* __restrict__ gold) {
  __shared__ __align__(16) ushort Asl[64 * LDP];
  __shared__ __align__(16) ushort Bsl[64 * LDP];
  __shared__ int goldcol[64];
  __shared__ float pm[64][2], ps[64][2];
  const int vb = blockIdx.x, by = blockIdx.y;
  const int cb = vb * 64, rb = by * 64;
  if (threadIdx.x < 64) goldcol[threadIdx.x] = tgt[(by + 1) * B + threadIdx.x];
  MFMA_TILE_BODY((const ushort*)outs_bf, (const ushort*)Wv, rb, cb)
  #pragma unroll
  for (int m = 0; m < 2; m++) {
    #pragma unroll
    for (int r = 0; r < 4; r++) {
      int row_local = wr * 32 + m * 16 + l4 * 4 + r;
      int gc = goldcol[row_local];
      #pragma unroll
      for (int n = 0; n < 2; n++) {
        int col = cb + wc * 32 + n * 16 + l15;
        if (col == gc) gold[rb + row_local] = acc[m][n][r];
      }
      float v = fmaxf(acc[m][0][r], acc[m][1][r]);
      #pragma unroll
      for (int o = 1; o < 16; o <<= 1) v = fmaxf(v, __shfl_xor(v, o));
      float e = __expf(acc[m][0][r] - v) + __expf(acc[m][1][r] - v);
      #pragma unroll
      for (int o = 1; o < 16; o <<= 1) e += __shfl_xor(e, o);
      if (l15 == 0) { pm[row_local][wc] = v; ps[row_local][wc] = e; }
    }
  }
  __syncthreads();
  if (tid < 64) {
    float m0 = pm[tid][0], m1 = pm[tid][1];
    float M = fmaxf(m0, m1);
    float Ss = ps[tid][0] * __expf(m0 - M) + ps[tid][1] * __expf(m1 - M);
    int n = rb + tid;
    part_max[(size_t)n * NCHUNK + vb] = M;
    part_sum[(size_t)n * NCHUNK + vb] = Ss;
  }
}

// ---------------- persistent encoder: one block per (b, dir), loops all 64 t --
// block 512: thread computes z[2tid], z[2tid+1] per step. Weights k-major bf16.
__global__ __launch_bounds__(512) void k_enc_persist(
    const float* __restrict__ XwF, const float* __restrict__ XwB,
    const __hip_bfloat16* __restrict__ WTf, const __hip_bfloat16* __restrict__ WTb,
    __hip_bfloat16* __restrict__ fwd_bf, __hip_bfloat16* __restrict__ bwd_bf,
    float* __restrict__ Hfin, float* __restrict__ Cfin) {
  const int b = blockIdx.x, dir = blockIdx.y;
  const int tid = threadIdx.x;
  __shared__ float h_lds[256];
  __shared__ float zz[1024];
  const ushort* WT = (const ushort*)(dir ? WTb : WTf);
  const float* Xw = dir ? XwB : XwF;
  if (tid < 256) h_lds[tid] = 0.f;
  float c_reg = 0.f;
  __syncthreads();
  for (int st = 0; st < 64; st++) {
    const int ts = dir ? (63 - st) : st;
    float a0 = 0.f, a1 = 0.f;
    const ushort* wp = WT + 2 * tid;
    #pragma unroll 4
    for (int k = 0; k < 256; k += 4) {
      float4 hv = *(const float4*)&h_lds[k];
      uint w0 = *(const uint*)(wp + (size_t)(k + 0) * 1024);
      uint w1 = *(const uint*)(wp + (size_t)(k + 1) * 1024);
      uint w2 = *(const uint*)(wp + (size_t)(k + 2) * 1024);
      uint w3 = *(const uint*)(wp + (size_t)(k + 3) * 1024);
      a0 += bflo(w0) * hv.x + bflo(w1) * hv.y + bflo(w2) * hv.z + bflo(w3) * hv.w;
      a1 += bfhi(w0) * hv.x + bfhi(w1) * hv.y + bfhi(w2) * hv.z + bfhi(w3) * hv.w;
    }
    zz[2 * tid] = a0;
    zz[2 * tid + 1] = a1;
    __syncthreads();
    if (tid < 256) {
      const float* xw = Xw + (size_t)(ts * 64 + b) * 1024;
      float zi = zz[tid] + xw[tid];
      float zf = zz[256 + tid] + xw[256 + tid];
      float zg = zz[512 + tid] + xw[512 + tid];
      float zo = zz[768 + tid] + xw[768 + tid];
      c_reg = sigf(zf) * c_reg + sigf(zi) * tanhfast(zg);
      float h = sigf(zo) * tanhfast(c_reg);
      h_lds[tid] = h;
      __hip_bfloat16 hb = __float2bfloat16(h);
      if (dir == 0) fwd_bf[(st * 64 + b) * 256 + tid] = hb;
      else          bwd_bf[((63 - st) * 64 + b) * 256 + tid] = hb;
    }
    __syncthreads();
  }
  if (tid < 256) {
    Hfin[(dir * 64 + b) * 256 + tid] = h_lds[tid];
    Cfin[(dir * 64 + b) * 256 + tid] = c_reg;
  }
}

// ---------------- decoder init: dec_h = [hf|hb]Wh^T, dec_c = [cf|cb]Wc^T ------
__global__ __launch_bounds__(256) void k_dec_init(
    const float* __restrict__ Hfin, const float* __restrict__ Cfin,
    const float* __restrict__ Wh, const float* __restrict__ Wc,
    float* __restrict__ dech0, float* __restrict__ decc0) {
  int b = blockIdx.x, tid = threadIdx.x;
  __shared__ __align__(16) float ch[512], cc[512];
  ch[tid]       = Hfin[(0 * 64 + b) * 256 + tid];
  ch[256 + tid] = Hfin[(1 * 64 + b) * 256 + tid];
  cc[tid]       = Cfin[(0 * 64 + b) * 256 + tid];
  cc[256 + tid] = Cfin[(1 * 64 + b) * 256 + tid];
  __syncthreads();
  const float* wh = Wh + tid * 512;
  const float* wc = Wc + tid * 512;
  float ah = 0, ac = 0;
  for (int k = 0; k < 512; k += 4) {
    float4 hv = *(const float4*)&ch[k];
    float4 cv = *(const float4*)&cc[k];
    float4 w1 = *(const float4*)&wh[k];
    float4 w2 = *(const float4*)&wc[k];
    ah += hv.x * w1.x + hv.y * w1.y + hv.z * w1.z + hv.w * w1.w;
    ac += cv.x * w2.x + cv.y * w2.y + cv.z * w2.z + cv.w * w2.w;
  }
  dech0[b * 256 + tid] = ah;
  decc0[b * 256 + tid] = ac;
}

// ---------------- enc_proj[b][s][j] ------------------------------------------
__global__ __launch_bounds__(256) void k_enc_proj(
    const __hip_bfloat16* __restrict__ fwd_bf, const __hip_bfloat16* __restrict__ bwd_bf,
    const float* __restrict__ Watt, __hip_bfloat16* __restrict__ encproj_bf) {
  int b = blockIdx.x, s = blockIdx.y, tid = threadIdx.x;
  __shared__ __align__(16) float eh[512];
  eh[tid]       = __bfloat162float(fwd_bf[(s * B + b) * H + tid]);
  eh[256 + tid] = __bfloat162float(bwd_bf[(s * B + b) * H + tid]);
  __syncthreads();
  const float* w = Watt + tid * 512;
  float acc = 0;
  for (int k = 0; k < 512; k += 4) {
    float4 xv = *(const float4*)&eh[k];
    float4 wv = *(const float4*)&w[k];
    acc += xv.x * wv.x + xv.y * wv.y + xv.z * wv.z + xv.w * wv.w;
  }
  encproj_bf[(b * S + s) * H + tid] = __float2bfloat16(acc);
}

// ---------------- persistent decoder: one block per b, loops all 63 t ---------
// block 512. zWT [512][1024] bf16 (k-major: rows 0-255 = dWhh, 256-511 = dWih o-part).
// WcT [768][256] bf16 (k-major Wcomb). encproj [b][s][256] bf16.
__global__ __launch_bounds__(512) void k_dec_persist(
    const float* __restrict__ YW, const __hip_bfloat16* __restrict__ zWT,
    const __hip_bfloat16* __restrict__ WcT, const __hip_bfloat16* __restrict__ encproj_bf,
    const __hip_bfloat16* __restrict__ fwd_bf, const __hip_bfloat16* __restrict__ bwd_bf,
    const float* __restrict__ dech0, const float* __restrict__ decc0,
    __hip_bfloat16* __restrict__ outs_bf) {
  const int b = blockIdx.x, tid = threadIdx.x;
  __shared__ float h_lds[256], O_lds[256];
  __shared__ __align__(16) float a_lds[512];
  __shared__ float zzp[2][1024];
  __shared__ float ps[64][8];
  __shared__ float alpha_lds[64];
  __shared__ float op[2][256];
  if (tid < 256) {
    h_lds[tid] = dech0[b * 256 + tid];
    O_lds[tid] = 0.f;
  }
  float c_reg = (tid < 256) ? decc0[b * 256 + tid] : 0.f;
  __syncthreads();
  const int jg = tid & 255, half = tid >> 8;
  for (int t = 0; t < 63; t++) {
    // ---- phase 1: z partial dots (j-quad per thread, k-half per wave-group)
    {
      float a0 = 0.f, a1 = 0.f, a2 = 0.f, a3 = 0.f;
      const ushort* wp = (const ushort*)zWT + (size_t)half * 256 * 1024 + 4 * jg;
      const float* xsrc = half ? O_lds : h_lds;
      #pragma unroll 4
      for (int k = 0; k < 256; k++) {
        float x = xsrc[k];
        uint2 w = *(const uint2*)(wp + (size_t)k * 1024);
        a0 += bflo(w.x) * x;
        a1 += bfhi(w.x) * x;
        a2 += bflo(w.y) * x;
        a3 += bfhi(w.y) * x;
      }
      zzp[half][4 * jg + 0] = a0;
      zzp[half][4 * jg + 1] = a1;
      zzp[half][4 * jg + 2] = a2;
      zzp[half][4 * jg + 3] = a3;
    }
    __syncthreads();
    // ---- LSTM update (threads 0..255)
    if (tid < 256) {
      const float* yw = YW + (size_t)(t * 64 + b) * 1024;
      float zi = zzp[0][tid] + zzp[1][tid] + yw[tid];
      float zf = zzp[0][256 + tid] + zzp[1][256 + tid] + yw[256 + tid];
      float zg = zzp[0][512 + tid] + zzp[1][512 + tid] + yw[512 + tid];
      float zo = zzp[0][768 + tid] + zzp[1][768 + tid] + yw[768 + tid];
      c_reg = sigf(zf) * c_reg + sigf(zi) * tanhfast(zg);
      h_lds[tid] = sigf(zo) * tanhfast(c_reg);
    }
    __syncthreads();
    // ---- e partials: s = tid>>3, q = tid&7 (32-k chunk each)
    {
      int s = tid >> 3, q = tid & 7;
      const ushort* pr = (const ushort*)encproj_bf + (size_t)(b * 64 + s) * 256 + 32 * q;
      const float* hq = &h_lds[32 * q];
      float acc = 0.f;
      #pragma unroll 4
      for (int k = 0; k < 32; k += 2) {
        uint w = *(const uint*)(pr + k);
        acc += bflo(w) * hq[k] + bfhi(w) * hq[k + 1];
      }
      ps[s][q] = acc;
    }
    __syncthreads();
    // ---- softmax over s (wave 0)
    if (tid < 64) {
      float e = 0.f;
      #pragma unroll
      for (int q = 0; q < 8; q++) e += ps[tid][q];
      float m = e;
      #pragma unroll
      for (int o = 32; o > 0; o >>= 1) m = fmaxf(m, __shfl_xor(m, o));
      float p = __expf(e - m);
      float ss = p;
      #pragma unroll
      for (int o = 32; o > 0; o >>= 1) ss += __shfl_xor(ss, o);
      alpha_lds[tid] = p / ss;
    }
    __syncthreads();
    // ---- a_t: thread owns dim d = tid (0..511): fwd cols then bwd cols
    {
      const ushort* basep = (tid < 256)
          ? ((const ushort*)fwd_bf + b * 256 + tid)
          : ((const ushort*)bwd_bf + b * 256 + (tid - 256));
      float acc = 0.f;
      #pragma unroll 4
      for (int s = 0; s < 64; s++)
        acc += alpha_lds[s] * __uint_as_float(((uint)basep[(size_t)s * 16384]) << 16);
      a_lds[tid] = acc;
    }
    __syncthreads();
    // ---- O = tanh([a|h] WcombT): thread j = tid&255, k-half per wave-group
    {
      const ushort* wp = (const ushort*)WcT + jg;
      float acc = 0.f;
      if (half == 0) {
        #pragma unroll 4
        for (int k = 0; k < 384; k++)
          acc += a_lds[k] * __uint_as_float(((uint)wp[(size_t)k * 256]) << 16);
      } else {
        #pragma unroll 4
        for (int k = 384; k < 512; k++)
          acc += a_lds[k] * __uint_as_float(((uint)wp[(size_t)k * 256]) << 16);
        #pragma unroll 4
        for (int k = 512; k < 768; k++)
          acc += h_lds[k - 512] * __uint_as_float(((uint)wp[(size_t)k * 256]) << 16);
      }
      op[half][jg] = acc;
    }
    __syncthreads();
    if (tid < 256) {
      float O = tanhfast(op[0][tid] + op[1][tid]);
      O_lds[tid] = O;
      outs_bf[(size_t)(t * 64 + b) * 256 + tid] = __float2bfloat16(O);
    }
    __syncthreads();
  }
}

// ---------------- final reduce ------------------------------------------------
__global__ __launch_bounds__(256) void k_final(
    const float* __restrict__ part_max, const float* __restrict__ part_sum,
    const float* __restrict__ gold, const int* __restrict__ tgt,
    float* __restrict__ out) {
  int b = blockIdx.x, tid = threadIdx.x;
  int tq = tid >> 2, q = tid & 3;
  __shared__ float lm[64][4], ls[64][4];
  __shared__ float red[64];
  if (tq < T - 1) {
    int n = tq * B + b;
    float m = -__builtin_inff(), s = 0;
    for (int i = q; i < NCHUNK; i += 4) {
      float pmv = part_max[(size_t)n * NCHUNK + i];
      float psv = part_sum[(size_t)n * NCHUNK + i];
      float M2 = fmaxf(m, pmv);
      s = s * __expf(m - M2) + psv * __expf(pmv - M2);
      m = M2;
    }
    lm[tq][q] = m;
    ls[tq][q] = s;
  }
  __syncthreads();
  if (tid < T - 1) {
    float M = fmaxf(fmaxf(lm[tid][0], lm[tid][1]), fmaxf(lm[tid][2], lm[tid][3]));
    float Ss = ls[tid][0] * __expf(lm[tid][0] - M) + ls[tid][1] * __expf(lm[tid][1] - M) +
               ls[tid][2] * __expf(lm[tid][2] - M) + ls[tid][3] * __expf(lm[tid][3] - M);
    float lse = M + logf(Ss);
    int g = tgt[(tid + 1) * B + b];
    red[tid] = (g != 0) ? (gold[tid * B + b] - lse) : 0.f;
  }
  if (tid == T - 1) red[T - 1] = 0.f;
  __syncthreads();
  if (tid == 0) {
    float s = 0;
    for (int i = 0; i < T - 1; i++) s += red[i];
    out[b] = s;
  }
}

extern "C" void kernel_launch(void* const* d_in, const int* in_sizes, int n_in,
                              void* d_out, int out_size, void* d_ws, size_t ws_size,
                              hipStream_t stream) {
  (void)in_sizes; (void)n_in; (void)out_size; (void)ws_size;
  const int*   src   = (const int*)  d_in[0];
  const int*   tgt   = (const int*)  d_in[1];
  const float* semb  = (const float*)d_in[2];
  const float* temb  = (const float*)d_in[3];
  const float* WihF  = (const float*)d_in[4];
  const float* WhhF  = (const float*)d_in[5];
  const float* bF    = (const float*)d_in[6];
  const float* WihB  = (const float*)d_in[7];
  const float* WhhB  = (const float*)d_in[8];
  const float* bB    = (const float*)d_in[9];
  const float* dWih  = (const float*)d_in[10];
  const float* dWhh  = (const float*)d_in[11];
  const float* db    = (const float*)d_in[12];
  const float* Wh    = (const float*)d_in[13];
  const float* Wc    = (const float*)d_in[14];
  const float* Watt  = (const float*)d_in[15];
  const float* Wcomb = (const float*)d_in[16];
  const float* Wv    = (const float*)d_in[17];
  float* out = (float*)d_out;

  char* wp = (char*)d_ws;
  auto alloc = [&](size_t bytes) -> char* {
    char* p = wp;
    wp += (bytes + 255) & ~(size_t)255;
    return p;
  };
  float* XwF  = (float*)alloc((size_t)S * B * H4 * 4);
  float* XwB  = (float*)alloc((size_t)S * B * H4 * 4);
  float* YW   = (float*)alloc((size_t)(T - 1) * B * H4 * 4);
  __hip_bfloat16* fwd_bf     = (__hip_bfloat16*)alloc((size_t)S * B * H * 2);
  __hip_bfloat16* bwd_bf     = (__hip_bfloat16*)alloc((size_t)S * B * H * 2);
  __hip_bfloat16* encproj_bf = (__hip_bfloat16*)alloc((size_t)B * S * H * 2);
  __hip_bfloat16* Ag         = (__hip_bfloat16*)alloc((size_t)S * B * E * 2);
  __hip_bfloat16* Yg         = (__hip_bfloat16*)alloc((size_t)(T - 1) * B * E * 2);
  __hip_bfloat16* WihF_bf    = (__hip_bfloat16*)alloc((size_t)H4 * E * 2);
  __hip_bfloat16* WihB_bf    = (__hip_bfloat16*)alloc((size_t)H4 * E * 2);
  __hip_bfloat16* dWih_bf    = (__hip_bfloat16*)alloc((size_t)H4 * E * 2);
  __hip_bfloat16* Wv_bf      = (__hip_bfloat16*)alloc((size_t)V * H * 2);
  __hip_bfloat16* outs_bf    = (__hip_bfloat16*)alloc((size_t)NROW * H * 2);
  __hip_bfloat16* WTf        = (__hip_bfloat16*)alloc((size_t)256 * 1024 * 2);
  __hip_bfloat16* WTb        = (__hip_bfloat16*)alloc((size_t)256 * 1024 * 2);
  __hip_bfloat16* zWT        = (__hip_bfloat16*)alloc((size_t)512 * 1024 * 2);
  __hip_bfloat16* WcT        = (__hip_bfloat16*)alloc((size_t)768 * 256 * 2);
  float* part_max = (float*)alloc((size_t)NROW * NCHUNK * 4);
  float* part_sum = (float*)alloc((size_t)NROW * NCHUNK * 4);
  float* gold     = (float*)alloc((size_t)NROW * 4);
  float* Hfin  = (float*)alloc((size_t)2 * B * H * 4);
  float* Cfin  = (float*)alloc((size_t)2 * B * H * 4);
  float* dech0 = (float*)alloc((size_t)B * H * 4);
  float* decc0 = (float*)alloc((size_t)B * H * 4);

  // converts + gathers + weight transposes
  hipLaunchKernelGGL(k_cvt_bf16, dim3((H4 * E + 255) / 256), dim3(256), 0, stream,
                     WihF, WihF_bf, H4 * E);
  hipLaunchKernelGGL(k_cvt_bf16, dim3((H4 * E + 255) / 256), dim3(256), 0, stream,
                     WihB, WihB_bf, H4 * E);
  hipLaunchKernelGGL(k_cvt_slice, dim3(H4), dim3(256), 0, stream, dWih, dWih_bf);
  hipLaunchKernelGGL(k_cvt_bf16, dim3((V * H + 255) / 256), dim3(256), 0, stream,
                     Wv, Wv_bf, V * H);
  hipLaunchKernelGGL(k_gather, dim3(S * B), dim3(256), 0, stream, src, semb, Ag);
  hipLaunchKernelGGL(k_gather, dim3((T - 1) * B), dim3(256), 0, stream, tgt, temb, Yg);
  hipLaunchKernelGGL(k_wt, dim3(16, 4), dim3(256), 0, stream, WhhF, WTf, 1024, 256, 0);
  hipLaunchKernelGGL(k_wt, dim3(16, 4), dim3(256), 0, stream, WhhB, WTb, 1024, 256, 0);
  hipLaunchKernelGGL(k_wt, dim3(16, 4), dim3(256), 0, stream, dWhh, zWT, 1024, 256, 0);
  hipLaunchKernelGGL(k_wt, dim3(16, 4), dim3(256), 0, stream, dWih,
                     zWT + (size_t)256 * 1024, 1024, 512, 256);
  hipLaunchKernelGGL(k_wt, dim3(4, 12), dim3(256), 0, stream, Wcomb, WcT, 256, 768, 0);

  // input GEMMs (MFMA)
  hipLaunchKernelGGL(k_gemm_bias, dim3(H4 / 64, S * B / 64), dim3(256), 0, stream,
                     Ag, WihF_bf, bF, XwF, H4);
  hipLaunchKernelGGL(k_gemm_bias, dim3(H4 / 64, S * B / 64), dim3(256), 0, stream,
                     Ag, WihB_bf, bB, XwB, H4);
  hipLaunchKernelGGL(k_gemm_bias, dim3(H4 / 64, (T - 1) * B / 64), dim3(256), 0, stream,
                     Yg, dWih_bf, db, YW, H4);

  // persistent encoder (both dirs), decoder init, enc projection
  hipLaunchKernelGGL(k_enc_persist, dim3(B, 2), dim3(512), 0, stream,
                     XwF, XwB, WTf, WTb, fwd_bf, bwd_bf, Hfin, Cfin);
  hipLaunchKernelGGL(k_dec_init, dim3(B), dim3(256), 0, stream,
                     Hfin, Cfin, Wh, Wc, dech0, decc0);
  hipLaunchKernelGGL(k_enc_proj, dim3(B, S), dim3(256), 0, stream,
                     fwd_bf, bwd_bf, Watt, encproj_bf);

  // persistent decoder (LSTM + attention + combine, all 63 steps)
  hipLaunchKernelGGL(k_dec_persist, dim3(B), dim3(512), 0, stream,
                     YW, zWT, WcT, encproj_bf, fwd_bf, bwd_bf, dech0, decc0, outs_bf);

  // vocab projection + log-softmax partials + final reduce
  hipLaunchKernelGGL(k_vocab_mfma, dim3(NCHUNK, T - 1), dim3(256), 0, stream,
                     outs_bf, Wv_bf, tgt, part_max, part_sum, gold);
  hipLaunchKernelGGL(k_final, dim3(B), dim3(256), 0, stream,
                     part_max, part_sum, gold, tgt, out);
}

// Round 4
// 2743.243 us; speedup vs baseline: 1.1845x; 1.1845x over previous
//
#include <hip/hip_runtime.h>
#include <hip/hip_bf16.h>

static constexpr int S = 64, T = 64, B = 64, E = 256, H = 256, V = 32000;
static constexpr int H4 = 4 * H;          // 1024
static constexpr int NCHUNK = 500;        // V / 64
static constexpr int NROW = (T - 1) * B;  // 4032
static constexpr int LDP = 264;           // LDS row stride (bf16 elems) for MFMA tiles

typedef short bf16x8 __attribute__((ext_vector_type(8)));
typedef float f32x4 __attribute__((ext_vector_type(4)));

__device__ __forceinline__ float sigf(float x) { return 1.0f / (1.0f + __expf(-x)); }
__device__ __forceinline__ float tanhfast(float x) { return 1.0f - 2.0f / (__expf(2.0f * x) + 1.0f); }
__device__ __forceinline__ float bflo(uint w) { return __uint_as_float(w << 16); }
__device__ __forceinline__ float bfhi(uint w) { return __uint_as_float(w & 0xffff0000u); }

// ---------------- f32 -> bf16 convert (flat) ----------------
__global__ __launch_bounds__(256) void k_cvt_bf16(const float* __restrict__ src,
                                                  __hip_bfloat16* __restrict__ dst, int n) {
  int i = blockIdx.x * 256 + threadIdx.x;
  if (i < n) dst[i] = __float2bfloat16(src[i]);
}

// ---------------- f32 [N][512] -> bf16 [N][256] (first-256 slice) -------------
__global__ __launch_bounds__(256) void k_cvt_slice(const float* __restrict__ src,
                                                   __hip_bfloat16* __restrict__ dst) {
  int n = blockIdx.x, tid = threadIdx.x;
  dst[n * 256 + tid] = __float2bfloat16(src[n * 512 + tid]);
}

// ---------------- embedding gather -> bf16 [rows][256] ------------------------
__global__ __launch_bounds__(256) void k_gather(const int* __restrict__ idx,
                                                const float* __restrict__ emb,
                                                __hip_bfloat16* __restrict__ dst) {
  int r = blockIdx.x, tid = threadIdx.x;
  dst[r * 256 + tid] = __float2bfloat16(emb[idx[r] * E + tid]);
}

// ---------------- quad-k pack: dst[i][j] = bf16 src[j][off+4i..4i+3] ----------
// dst is uint2 [K/4][J], J = 1<<jshift. total = (K/4)*J threads.
__global__ __launch_bounds__(256) void k_pack4(const float* __restrict__ src,
                                               uint2* __restrict__ dst,
                                               int total, int jshift, int ld, int off) {
  int idx = blockIdx.x * 256 + threadIdx.x;
  if (idx >= total) return;
  int J = 1 << jshift;
  int i = idx >> jshift, j = idx & (J - 1);
  const float* s = src + (size_t)j * ld + off + 4 * i;
  float4 v = *(const float4*)s;
  ushort a = __bfloat16_as_ushort(__float2bfloat16(v.x));
  ushort b = __bfloat16_as_ushort(__float2bfloat16(v.y));
  ushort c = __bfloat16_as_ushort(__float2bfloat16(v.z));
  ushort d = __bfloat16_as_ushort(__float2bfloat16(v.w));
  uint2 o;
  o.x = (uint)a | ((uint)b << 16);
  o.y = (uint)c | ((uint)d << 16);
  dst[(size_t)i * J + j] = o;
}

// ============ shared MFMA 64x64 tile core (K=256, bf16 in, f32 acc) ===========
#define MFMA_TILE_BODY(Abase, Wbase, rb, cb)                                     \
  const int tid = threadIdx.x;                                                   \
  const int lane = tid & 63, wid = tid >> 6;                                     \
  const int wr = wid >> 1, wc = wid & 1;                                         \
  const int l15 = lane & 15, l4 = lane >> 4;                                     \
  for (int it = 0; it < 8; it++) {                                               \
    int c = it * 256 + tid;                                                      \
    int row = c >> 5, off = (c & 31) * 8;                                        \
    *(uint4*)&Asl[row * LDP + off] =                                             \
        *(const uint4*)((Abase) + (size_t)((rb) + row) * 256 + off);             \
    *(uint4*)&Bsl[row * LDP + off] =                                             \
        *(const uint4*)((Wbase) + (size_t)((cb) + row) * 256 + off);             \
  }                                                                              \
  __syncthreads();                                                               \
  f32x4 acc[2][2];                                                               \
  for (int m = 0; m < 2; m++)                                                    \
    for (int n = 0; n < 2; n++) acc[m][n] = (f32x4){0.f, 0.f, 0.f, 0.f};         \
  for (int kk = 0; kk < 8; kk++) {                                               \
    int ko = kk * 32 + l4 * 8;                                                   \
    bf16x8 a0 = *(const bf16x8*)&Asl[(wr * 32 + l15) * LDP + ko];                \
    bf16x8 a1 = *(const bf16x8*)&Asl[(wr * 32 + 16 + l15) * LDP + ko];           \
    bf16x8 b0 = *(const bf16x8*)&Bsl[(wc * 32 + l15) * LDP + ko];                \
    bf16x8 b1 = *(const bf16x8*)&Bsl[(wc * 32 + 16 + l15) * LDP + ko];           \
    acc[0][0] = __builtin_amdgcn_mfma_f32_16x16x32_bf16(a0, b0, acc[0][0], 0, 0, 0); \
    acc[0][1] = __builtin_amdgcn_mfma_f32_16x16x32_bf16(a0, b1, acc[0][1], 0, 0, 0); \
    acc[1][0] = __builtin_amdgcn_mfma_f32_16x16x32_bf16(a1, b0, acc[1][0], 0, 0, 0); \
    acc[1][1] = __builtin_amdgcn_mfma_f32_16x16x32_bf16(a1, b1, acc[1][1], 0, 0, 0); \
  }

// ---------------- generic GEMM + bias: C f32 = A x W^T + bias -----------------
__global__ __launch_bounds__(256) void k_gemm_bias(
    const __hip_bfloat16* __restrict__ A, const __hip_bfloat16* __restrict__ W,
    const float* __restrict__ bias, float* __restrict__ C, int ldc) {
  __shared__ __align__(16) ushort Asl[64 * LDP];
  __shared__ __align__(16) ushort Bsl[64 * LDP];
  const int cb = blockIdx.x * 64, rb = blockIdx.y * 64;
  MFMA_TILE_BODY((const ushort*)A, (const ushort*)W, rb, cb)
  #pragma unroll
  for (int m = 0; m < 2; m++)
    #pragma unroll
    for (int n = 0; n < 2; n++) {
      int col = cb + wc * 32 + n * 16 + l15;
      float bv = bias[col];
      #pragma unroll
      for (int r = 0; r < 4; r++) {
        int row = rb + wr * 32 + m * 16 + l4 * 4 + r;
        C[(size_t)row * ldc + col] = acc[m][n][r] + bv;
      }
    }
}

// ---------------- vocab GEMM + fused chunk logsumexp + gold capture -----------
__global__ __launch_bounds__(256) void k_vocab_mfma(
    const __hip_bfloat16* __restrict__ outs_bf, const __hip_bfloat16* __restrict__ Wv,
    const int* __restrict__ tgt, float* __restrict__ part_max,
    float* __restrict__ part_sum, float* __restrict__ gold) {
  __shared__ __align__(16) ushort Asl[64 * LDP];
  __shared__ __align__(16) ushort Bsl[64 * LDP];
  __shared__ int goldcol[64];
  __shared__ float pm[64][2], ps[64][2];
  const int vb = blockIdx.x, by = blockIdx.y;
  const int cb = vb * 64, rb = by * 64;
  if (threadIdx.x < 64) goldcol[threadIdx.x] = tgt[(by + 1) * B + threadIdx.x];
  MFMA_TILE_BODY((const ushort*)outs_bf, (const ushort*)Wv, rb, cb)
  #pragma unroll
  for (int m = 0; m < 2; m++) {
    #pragma unroll
    for (int r = 0; r < 4; r++) {
      int row_local = wr * 32 + m * 16 + l4 * 4 + r;
      int gc = goldcol[row_local];
      #pragma unroll
      for (int n = 0; n < 2; n++) {
        int col = cb + wc * 32 + n * 16 + l15;
        if (col == gc) gold[rb + row_local] = acc[m][n][r];
      }
      float v = fmaxf(acc[m][0][r], acc[m][1][r]);
      #pragma unroll
      for (int o = 1; o < 16; o <<= 1) v = fmaxf(v, __shfl_xor(v, o));
      float e = __expf(acc[m][0][r] - v) + __expf(acc[m][1][r] - v);
      #pragma unroll
      for (int o = 1; o < 16; o <<= 1) e += __shfl_xor(e, o);
      if (l15 == 0) { pm[row_local][wc] = v; ps[row_local][wc] = e; }
    }
  }
  __syncthreads();
  if (tid < 64) {
    float m0 = pm[tid][0], m1 = pm[tid][1];
    float M = fmaxf(m0, m1);
    float Ss = ps[tid][0] * __expf(m0 - M) + ps[tid][1] * __expf(m1 - M);
    int n = rb + tid;
    part_max[(size_t)n * NCHUNK + vb] = M;
    part_sum[(size_t)n * NCHUNK + vb] = Ss;
  }
}

// ---------------- persistent encoder: block 1024, grid (64, 2) ----------------
// Thread owns z-column tid. Wq: uint2 [64][1024], quad-k packed.
__global__ __launch_bounds__(1024) void k_enc_persist(
    const float* __restrict__ XwF, const float* __restrict__ XwB,
    const uint2* __restrict__ Wq_f, const uint2* __restrict__ Wq_b,
    __hip_bfloat16* __restrict__ fwd_bf, __hip_bfloat16* __restrict__ bwd_bf,
    float* __restrict__ Hfin, float* __restrict__ Cfin) {
  const int b = blockIdx.x, dir = blockIdx.y;
  const int tid = threadIdx.x;
  __shared__ __align__(16) float h_lds[256];
  __shared__ float zz[1024];
  const uint2* Wq = dir ? Wq_b : Wq_f;
  const float* Xw = dir ? XwB : XwF;
  if (tid < 256) h_lds[tid] = 0.f;
  float c_reg = 0.f;
  __syncthreads();
  for (int st = 0; st < 64; st++) {
    const int ts = dir ? (63 - st) : st;
    {
      float a0 = 0.f, a1 = 0.f;
      const uint2* wp = Wq + tid;
      const float4* h4 = (const float4*)h_lds;
      #pragma unroll 8
      for (int i = 0; i < 64; i += 2) {
        uint2 w0 = wp[(size_t)i * 1024];
        uint2 w1 = wp[(size_t)(i + 1) * 1024];
        float4 v0 = h4[i];
        float4 v1 = h4[i + 1];
        a0 += bflo(w0.x) * v0.x + bfhi(w0.x) * v0.y + bflo(w0.y) * v0.z + bfhi(w0.y) * v0.w;
        a1 += bflo(w1.x) * v1.x + bfhi(w1.x) * v1.y + bflo(w1.y) * v1.z + bfhi(w1.y) * v1.w;
      }
      zz[tid] = a0 + a1;
    }
    __syncthreads();
    if (tid < 256) {
      const float* xw = Xw + (size_t)(ts * 64 + b) * 1024;
      float zi = zz[tid] + xw[tid];
      float zf = zz[256 + tid] + xw[256 + tid];
      float zg = zz[512 + tid] + xw[512 + tid];
      float zo = zz[768 + tid] + xw[768 + tid];
      c_reg = sigf(zf) * c_reg + sigf(zi) * tanhfast(zg);
      float h = sigf(zo) * tanhfast(c_reg);
      h_lds[tid] = h;
      __hip_bfloat16 hb = __float2bfloat16(h);
      if (dir == 0) fwd_bf[(st * 64 + b) * 256 + tid] = hb;
      else          bwd_bf[((63 - st) * 64 + b) * 256 + tid] = hb;
    }
    __syncthreads();
  }
  if (tid < 256) {
    Hfin[(dir * 64 + b) * 256 + tid] = h_lds[tid];
    Cfin[(dir * 64 + b) * 256 + tid] = c_reg;
  }
}

// ---------------- decoder init ------------------------------------------------
__global__ __launch_bounds__(256) void k_dec_init(
    const float* __restrict__ Hfin, const float* __restrict__ Cfin,
    const float* __restrict__ Wh, const float* __restrict__ Wc,
    float* __restrict__ dech0, float* __restrict__ decc0) {
  int b = blockIdx.x, tid = threadIdx.x;
  __shared__ __align__(16) float ch[512], cc[512];
  ch[tid]       = Hfin[(0 * 64 + b) * 256 + tid];
  ch[256 + tid] = Hfin[(1 * 64 + b) * 256 + tid];
  cc[tid]       = Cfin[(0 * 64 + b) * 256 + tid];
  cc[256 + tid] = Cfin[(1 * 64 + b) * 256 + tid];
  __syncthreads();
  const float* wh = Wh + tid * 512;
  const float* wc = Wc + tid * 512;
  float ah = 0, ac = 0;
  for (int k = 0; k < 512; k += 4) {
    float4 hv = *(const float4*)&ch[k];
    float4 cv = *(const float4*)&cc[k];
    float4 w1 = *(const float4*)&wh[k];
    float4 w2 = *(const float4*)&wc[k];
    ah += hv.x * w1.x + hv.y * w1.y + hv.z * w1.z + hv.w * w1.w;
    ac += cv.x * w2.x + cv.y * w2.y + cv.z * w2.z + cv.w * w2.w;
  }
  dech0[b * 256 + tid] = ah;
  decc0[b * 256 + tid] = ac;
}

// ---------------- enc_proj[b][s][j] ------------------------------------------
__global__ __launch_bounds__(256) void k_enc_proj(
    const __hip_bfloat16* __restrict__ fwd_bf, const __hip_bfloat16* __restrict__ bwd_bf,
    const float* __restrict__ Watt, __hip_bfloat16* __restrict__ encproj_bf) {
  int b = blockIdx.x, s = blockIdx.y, tid = threadIdx.x;
  __shared__ __align__(16) float eh[512];
  eh[tid]       = __bfloat162float(fwd_bf[(s * B + b) * H + tid]);
  eh[256 + tid] = __bfloat162float(bwd_bf[(s * B + b) * H + tid]);
  __syncthreads();
  const float* w = Watt + tid * 512;
  float acc = 0;
  for (int k = 0; k < 512; k += 4) {
    float4 xv = *(const float4*)&eh[k];
    float4 wv = *(const float4*)&w[k];
    acc += xv.x * wv.x + xv.y * wv.y + xv.z * wv.z + xv.w * wv.w;
  }
  encproj_bf[(b * S + s) * H + tid] = __float2bfloat16(acc);
}

// ---------------- persistent decoder: block 1024, grid (64) -------------------
// zWq: uint2 [128][1024] (k quads; k<256 = h·dWhh, k>=256 = O·dWih[:,256:]).
// Wcq: uint2 [192][256]  (Wcomb quad-k packed).
__global__ __launch_bounds__(1024) void k_dec_persist(
    const float* __restrict__ YW, const uint2* __restrict__ zWq,
    const uint2* __restrict__ Wcq, const __hip_bfloat16* __restrict__ encproj_bf,
    const __hip_bfloat16* __restrict__ fwd_bf, const __hip_bfloat16* __restrict__ bwd_bf,
    const float* __restrict__ dech0, const float* __restrict__ decc0,
    __hip_bfloat16* __restrict__ outs_bf) {
  const int b = blockIdx.x, tid = threadIdx.x;
  __shared__ __align__(16) float h_lds[256], O_lds[256];
  __shared__ float zz[1024];
  __shared__ __align__(16) float xcomb[768];
  __shared__ float e_lds[64], alpha_lds[64];
  __shared__ float ap[2][512];
  __shared__ float op[4][256];
  if (tid < 256) {
    h_lds[tid] = dech0[b * 256 + tid];
    O_lds[tid] = 0.f;
  }
  float c_reg = (tid < 256) ? decc0[b * 256 + tid] : 0.f;
  __syncthreads();
  for (int t = 0; t < 63; t++) {
    // ---- z = h·Whh^T + O·Wih_o^T (thread = column), k quad-packed ----
    {
      float a0 = 0.f, a1 = 0.f;
      const uint2* wp = zWq + tid;
      const float4* h4 = (const float4*)h_lds;
      const float4* o4 = (const float4*)O_lds;
      #pragma unroll 8
      for (int i = 0; i < 64; i += 2) {
        uint2 w0 = wp[(size_t)i * 1024];
        uint2 w1 = wp[(size_t)(i + 1) * 1024];
        float4 v0 = h4[i];
        float4 v1 = h4[i + 1];
        a0 += bflo(w0.x) * v0.x + bfhi(w0.x) * v0.y + bflo(w0.y) * v0.z + bfhi(w0.y) * v0.w;
        a1 += bflo(w1.x) * v1.x + bfhi(w1.x) * v1.y + bflo(w1.y) * v1.z + bfhi(w1.y) * v1.w;
      }
      #pragma unroll 8
      for (int i = 0; i < 64; i += 2) {
        uint2 w0 = wp[(size_t)(64 + i) * 1024];
        uint2 w1 = wp[(size_t)(65 + i) * 1024];
        float4 v0 = o4[i];
        float4 v1 = o4[i + 1];
        a0 += bflo(w0.x) * v0.x + bfhi(w0.x) * v0.y + bflo(w0.y) * v0.z + bfhi(w0.y) * v0.w;
        a1 += bflo(w1.x) * v1.x + bfhi(w1.x) * v1.y + bflo(w1.y) * v1.z + bfhi(w1.y) * v1.w;
      }
      zz[tid] = a0 + a1;
    }
    __syncthreads();
    // ---- LSTM gates (threads 0..255) ----
    if (tid < 256) {
      const float* yw = YW + (size_t)(t * 64 + b) * 1024;
      float zi = zz[tid] + yw[tid];
      float zf = zz[256 + tid] + yw[256 + tid];
      float zg = zz[512 + tid] + yw[512 + tid];
      float zo = zz[768 + tid] + yw[768 + tid];
      c_reg = sigf(zf) * c_reg + sigf(zi) * tanhfast(zg);
      h_lds[tid] = sigf(zo) * tanhfast(c_reg);
    }
    __syncthreads();
    // ---- e[s] = encproj[b][s][:]·h : s = tid>>4, q = tid&15 (16 k each) ----
    {
      int s = tid >> 4, q = tid & 15;
      const uint2* pr = (const uint2*)((const ushort*)encproj_bf + (size_t)(b * 64 + s) * 256) + q * 4;
      const float4* hq = (const float4*)(h_lds + q * 16);
      float a = 0.f;
      #pragma unroll
      for (int c = 0; c < 4; c++) {
        uint2 w = pr[c];
        float4 hv = hq[c];
        a += bflo(w.x) * hv.x + bfhi(w.x) * hv.y + bflo(w.y) * hv.z + bfhi(w.y) * hv.w;
      }
      #pragma unroll
      for (int o = 8; o > 0; o >>= 1) a += __shfl_xor(a, o);
      if (q == 0) e_lds[s] = a;
    }
    __syncthreads();
    // ---- softmax over s (wave 0) ----
    if (tid < 64) {
      float e = e_lds[tid];
      float m = e;
      #pragma unroll
      for (int o = 32; o > 0; o >>= 1) m = fmaxf(m, __shfl_xor(m, o));
      float p = __expf(e - m);
      float ss = p;
      #pragma unroll
      for (int o = 32; o > 0; o >>= 1) ss += __shfl_xor(ss, o);
      alpha_lds[tid] = p / ss;
    }
    __syncthreads();
    // ---- a_t[d] partials: d = tid&511, s-half = tid>>9 ----
    {
      int d = tid & 511, sh = tid >> 9;
      const ushort* basep = (d < 256)
          ? ((const ushort*)fwd_bf + b * 256 + d)
          : ((const ushort*)bwd_bf + b * 256 + (d - 256));
      float a = 0.f;
      #pragma unroll 8
      for (int s = sh * 32; s < sh * 32 + 32; s++)
        a += alpha_lds[s] * __uint_as_float(((uint)basep[(size_t)s * 16384]) << 16);
      ap[sh][d] = a;
    }
    __syncthreads();
    // ---- xcomb = [a(512) | h(256)] ----
    if (tid < 512) xcomb[tid] = ap[0][tid] + ap[1][tid];
    else if (tid < 768) xcomb[tid] = h_lds[tid - 512];
    __syncthreads();
    // ---- O = tanh(xcomb · Wcomb^T): j = tid&255, k-quarter = tid>>8 ----
    {
      int j = tid & 255, kq = tid >> 8;
      const uint2* wp2 = Wcq + j;
      const float4* x4 = (const float4*)xcomb;
      float a = 0.f;
      #pragma unroll 8
      for (int ii = 0; ii < 48; ii++) {
        int i = kq * 48 + ii;
        uint2 w = wp2[(size_t)i * 256];
        float4 xv = x4[i];
        a += bflo(w.x) * xv.x + bfhi(w.x) * xv.y + bflo(w.y) * xv.z + bfhi(w.y) * xv.w;
      }
      op[kq][j] = a;
    }
    __syncthreads();
    if (tid < 256) {
      float O = tanhfast(op[0][tid] + op[1][tid] + op[2][tid] + op[3][tid]);
      O_lds[tid] = O;
      outs_bf[(size_t)(t * 64 + b) * 256 + tid] = __float2bfloat16(O);
    }
    __syncthreads();
  }
}

// ---------------- final reduce ------------------------------------------------
__global__ __launch_bounds__(256) void k_final(
    const float* __restrict__ part_max, const float* __restrict__ part_sum,
    const float* __restrict__ gold, const int* __restrict__ tgt,
    float* __restrict__ out) {
  int b = blockIdx.x, tid = threadIdx.x;
  int tq = tid >> 2, q = tid & 3;
  __shared__ float lm[64][4], ls[64][4];
  __shared__ float red[64];
  if (tq < T - 1) {
    int n = tq * B + b;
    float m = -__builtin_inff(), s = 0;
    for (int i = q; i < NCHUNK; i += 4) {
      float pmv = part_max[(size_t)n * NCHUNK + i];
      float psv = part_sum[(size_t)n * NCHUNK + i];
      float M2 = fmaxf(m, pmv);
      s = s * __expf(m - M2) + psv * __expf(pmv - M2);
      m = M2;
    }
    lm[tq][q] = m;
    ls[tq][q] = s;
  }
  __syncthreads();
  if (tid < T - 1) {
    float M = fmaxf(fmaxf(lm[tid][0], lm[tid][1]), fmaxf(lm[tid][2], lm[tid][3]));
    float Ss = ls[tid][0] * __expf(lm[tid][0] - M) + ls[tid][1] * __expf(lm[tid][1] - M) +
               ls[tid][2] * __expf(lm[tid][2] - M) + ls[tid][3] * __expf(lm[tid][3] - M);
    float lse = M + logf(Ss);
    int g = tgt[(tid + 1) * B + b];
    red[tid] = (g != 0) ? (gold[tid * B + b] - lse) : 0.f;
  }
  if (tid == T - 1) red[T - 1] = 0.f;
  __syncthreads();
  if (tid == 0) {
    float s = 0;
    for (int i = 0; i < T - 1; i++) s += red[i];
    out[b] = s;
  }
}

extern "C" void kernel_launch(void* const* d_in, const int* in_sizes, int n_in,
                              void* d_out, int out_size, void* d_ws, size_t ws_size,
                              hipStream_t stream) {
  (void)in_sizes; (void)n_in; (void)out_size; (void)ws_size;
  const int*   src   = (const int*)  d_in[0];
  const int*   tgt   = (const int*)  d_in[1];
  const float* semb  = (const float*)d_in[2];
  const float* temb  = (const float*)d_in[3];
  const float* WihF  = (const float*)d_in[4];
  const float* WhhF  = (const float*)d_in[5];
  const float* bF    = (const float*)d_in[6];
  const float* WihB  = (const float*)d_in[7];
  const float* WhhB  = (const float*)d_in[8];
  const float* bB    = (const float*)d_in[9];
  const float* dWih  = (const float*)d_in[10];
  const float* dWhh  = (const float*)d_in[11];
  const float* db    = (const float*)d_in[12];
  const float* Wh    = (const float*)d_in[13];
  const float* Wc    = (const float*)d_in[14];
  const float* Watt  = (const float*)d_in[15];
  const float* Wcomb = (const float*)d_in[16];
  const float* Wv    = (const float*)d_in[17];
  float* out = (float*)d_out;

  char* wp = (char*)d_ws;
  auto alloc = [&](size_t bytes) -> char* {
    char* p = wp;
    wp += (bytes + 255) & ~(size_t)255;
    return p;
  };
  float* XwF  = (float*)alloc((size_t)S * B * H4 * 4);
  float* XwB  = (float*)alloc((size_t)S * B * H4 * 4);
  float* YW   = (float*)alloc((size_t)(T - 1) * B * H4 * 4);
  __hip_bfloat16* fwd_bf     = (__hip_bfloat16*)alloc((size_t)S * B * H * 2);
  __hip_bfloat16* bwd_bf     = (__hip_bfloat16*)alloc((size_t)S * B * H * 2);
  __hip_bfloat16* encproj_bf = (__hip_bfloat16*)alloc((size_t)B * S * H * 2);
  __hip_bfloat16* Ag         = (__hip_bfloat16*)alloc((size_t)S * B * E * 2);
  __hip_bfloat16* Yg         = (__hip_bfloat16*)alloc((size_t)(T - 1) * B * E * 2);
  __hip_bfloat16* WihF_bf    = (__hip_bfloat16*)alloc((size_t)H4 * E * 2);
  __hip_bfloat16* WihB_bf    = (__hip_bfloat16*)alloc((size_t)H4 * E * 2);
  __hip_bfloat16* dWih_bf    = (__hip_bfloat16*)alloc((size_t)H4 * E * 2);
  __hip_bfloat16* Wv_bf      = (__hip_bfloat16*)alloc((size_t)V * H * 2);
  __hip_bfloat16* outs_bf    = (__hip_bfloat16*)alloc((size_t)NROW * H * 2);
  uint2* Wq_f = (uint2*)alloc((size_t)64 * 1024 * 8);
  uint2* Wq_b = (uint2*)alloc((size_t)64 * 1024 * 8);
  uint2* zWq  = (uint2*)alloc((size_t)128 * 1024 * 8);
  uint2* Wcq  = (uint2*)alloc((size_t)192 * 256 * 8);
  float* part_max = (float*)alloc((size_t)NROW * NCHUNK * 4);
  float* part_sum = (float*)alloc((size_t)NROW * NCHUNK * 4);
  float* gold     = (float*)alloc((size_t)NROW * 4);
  float* Hfin  = (float*)alloc((size_t)2 * B * H * 4);
  float* Cfin  = (float*)alloc((size_t)2 * B * H * 4);
  float* dech0 = (float*)alloc((size_t)B * H * 4);
  float* decc0 = (float*)alloc((size_t)B * H * 4);

  // converts + gathers + weight packs
  hipLaunchKernelGGL(k_cvt_bf16, dim3((H4 * E + 255) / 256), dim3(256), 0, stream,
                     WihF, WihF_bf, H4 * E);
  hipLaunchKernelGGL(k_cvt_bf16, dim3((H4 * E + 255) / 256), dim3(256), 0, stream,
                     WihB, WihB_bf, H4 * E);
  hipLaunchKernelGGL(k_cvt_slice, dim3(H4), dim3(256), 0, stream, dWih, dWih_bf);
  hipLaunchKernelGGL(k_cvt_bf16, dim3((V * H + 255) / 256), dim3(256), 0, stream,
                     Wv, Wv_bf, V * H);
  hipLaunchKernelGGL(k_gather, dim3(S * B), dim3(256), 0, stream, src, semb, Ag);
  hipLaunchKernelGGL(k_gather, dim3((T - 1) * B), dim3(256), 0, stream, tgt, temb, Yg);
  hipLaunchKernelGGL(k_pack4, dim3(64 * 1024 / 256), dim3(256), 0, stream,
                     WhhF, Wq_f, 64 * 1024, 10, 256, 0);
  hipLaunchKernelGGL(k_pack4, dim3(64 * 1024 / 256), dim3(256), 0, stream,
                     WhhB, Wq_b, 64 * 1024, 10, 256, 0);
  hipLaunchKernelGGL(k_pack4, dim3(64 * 1024 / 256), dim3(256), 0, stream,
                     dWhh, zWq, 64 * 1024, 10, 256, 0);
  hipLaunchKernelGGL(k_pack4, dim3(64 * 1024 / 256), dim3(256), 0, stream,
                     dWih, zWq + (size_t)64 * 1024, 64 * 1024, 10, 512, 256);
  hipLaunchKernelGGL(k_pack4, dim3(192 * 256 / 256), dim3(256), 0, stream,
                     Wcomb, Wcq, 192 * 256, 8, 768, 0);

  // input GEMMs (MFMA)
  hipLaunchKernelGGL(k_gemm_bias, dim3(H4 / 64, S * B / 64), dim3(256), 0, stream,
                     Ag, WihF_bf, bF, XwF, H4);
  hipLaunchKernelGGL(k_gemm_bias, dim3(H4 / 64, S * B / 64), dim3(256), 0, stream,
                     Ag, WihB_bf, bB, XwB, H4);
  hipLaunchKernelGGL(k_gemm_bias, dim3(H4 / 64, (T - 1) * B / 64), dim3(256), 0, stream,
                     Yg, dWih_bf, db, YW, H4);

  // persistent encoder (both dirs), decoder init, enc projection
  hipLaunchKernelGGL(k_enc_persist, dim3(B, 2), dim3(1024), 0, stream,
                     XwF, XwB, Wq_f, Wq_b, fwd_bf, bwd_bf, Hfin, Cfin);
  hipLaunchKernelGGL(k_dec_init, dim3(B), dim3(256), 0, stream,
                     Hfin, Cfin, Wh, Wc, dech0, decc0);
  hipLaunchKernelGGL(k_enc_proj, dim3(B, S), dim3(256), 0, stream,
                     fwd_bf, bwd_bf, Watt, encproj_bf);

  // persistent decoder (LSTM + attention + combine, all 63 steps)
  hipLaunchKernelGGL(k_dec_persist, dim3(B), dim3(1024), 0, stream,
                     YW, zWq, Wcq, encproj_bf, fwd_bf, bwd_bf, dech0, decc0, outs_bf);

  // vocab projection + log-softmax partials + final reduce
  hipLaunchKernelGGL(k_vocab_mfma, dim3(NCHUNK, T - 1), dim3(256), 0, stream,
                     outs_bf, Wv_bf, tgt, part_max, part_sum, gold);
  hipLaunchKernelGGL(k_final, dim3(B), dim3(256), 0, stream,
                     part_max, part_sum, gold, tgt, out);
}